// Round 1
// baseline (96.202 us; speedup 1.0000x reference)
//
#include <hip/hip_runtime.h>

#define NQ 18
#define QDIM (1 << NQ)      // 262144
#define NBATCH 8
#define NLAYERS 4

// complex butterfly: a' = c*a + (-i s)*b ; b' = (-i s)*a + c*b
__device__ __forceinline__ void bfly(float2& a, float2& b, float c, float s) {
  float nax = c * a.x + s * b.y;
  float nay = c * a.y - s * b.x;
  float nbx = c * b.x + s * a.y;
  float nby = c * b.y - s * a.x;
  a.x = nax; a.y = nay; b.x = nbx; b.y = nby;
}

// butterfly across in-register index bit (xor mask m on vi)
__device__ __forceinline__ void regstage(float2* v, int m, float c, float s) {
#pragma unroll
  for (int vi = 0; vi < 32; ++vi)
    if (!(vi & m)) bfly(v[vi], v[vi | m], c, s);
}

// butterfly across a lane bit via shfl_xor; symmetric form: new = c*mine + (-i s)*other
__device__ __forceinline__ void shflstage(float2* v, int mask, float c, float s) {
#pragma unroll
  for (int k = 0; k < 32; ++k) {
    float ox = __shfl_xor(v[k].x, mask, 64);
    float oy = __shfl_xor(v[k].y, mask, 64);
    float nx = c * v[k].x + s * oy;
    float ny = c * v[k].y - s * ox;
    v[k].x = nx; v[k].y = ny;
  }
}

__device__ __forceinline__ void pmul(float2& a, float2 p) {  // a *= (p.x + i p.y)
  float nx = a.x * p.x - a.y * p.y;
  float ny = a.x * p.y + a.y * p.x;
  a.x = nx; a.y = ny;
}

// A-type tile layout (per wave, 2048 contiguous elems): e_local = r4<<7 | lane<<1 | c
// vi = 2*r4 + c  ->  element bit0 = vi bit0 ; element bits 7..10 = vi bits 1..4 ;
// element bits 1..6 = lane bits 0..5.  mixLow covers element bits 0..10.
__device__ __forceinline__ void mixLow(float2* v, float c, float s) {
  regstage(v, 1, c, s);
  shflstage(v, 1, c, s);  shflstage(v, 2, c, s);  shflstage(v, 4, c, s);
  shflstage(v, 8, c, s);  shflstage(v, 16, c, s); shflstage(v, 32, c, s);
  regstage(v, 2, c, s);   regstage(v, 4, c, s);
  regstage(v, 8, c, s);   regstage(v, 16, c, s);
}

// B-type comb layout (per wave): e = h<<11 | g<<4 | low3<<1 | c, h = r4<<3 | lane>>3
// element bits 14..17 = vi bits 1..4 ; element bits 11..13 = lane bits 3..5.
// mixHigh covers element bits 11..17.
__device__ __forceinline__ void mixHigh(float2* v, float c, float s) {
  shflstage(v, 8, c, s);  shflstage(v, 16, c, s); shflstage(v, 32, c, s);
  regstage(v, 2, c, s);   regstage(v, 4, c, s);
  regstage(v, 8, c, s);   regstage(v, 16, c, s);
}

__global__ void k_masks(const float* __restrict__ adj, unsigned* __restrict__ masks) {
  int b = blockIdx.x, u = threadIdx.x;
  if (u < NQ) {
    unsigned m = 0;
    const float* row = adj + ((size_t)b * NQ + u) * NQ;
    for (int vv = u + 1; vv < NQ; ++vv)
      if (row[vv] > 0.5f) m |= 1u << (NQ - 1 - vv);
    masks[b * NQ + u] = m;
  }
}

// MODE 0: generate state = e^{-i hp}/sqrt(dim), store hp u8, mixLow(beta[t0])
// MODE 1: load, mixLow(beta[t0]), phase, mixLow(beta[t0+1]), store
// MODE 2: load, mixLow(beta[t0]), energy reduction -> atomicAdd(out[b])
template <int MODE>
__global__ __launch_bounds__(256)
void k_passA(const float* __restrict__ betas, const unsigned* __restrict__ masks,
             unsigned char* __restrict__ hp8, float2* __restrict__ state,
             float* __restrict__ out, int t0) {
  __shared__ float2 ptab[160];
  __shared__ unsigned smask[NQ];
  const int tid = threadIdx.x;
  if (MODE != 2 && tid < 160) {
    float s, c; sincosf((float)tid, &s, &c);
    ptab[tid] = make_float2(c, -s);
  }
  const int T = blockIdx.x * 4 + (tid >> 6);
  const int b = T >> 7;
  const int g = T & 127;
  if (MODE == 0 && tid < NQ) smask[tid] = masks[b * NQ + tid];
  __syncthreads();
  const int lane = tid & 63;
  const size_t bbase = (size_t)b * QDIM;
  const int tbase = g * 2048;

  float2 v[32];
  const float cs0 = cosf(betas[b * NLAYERS + t0]);
  const float sn0 = sinf(betas[b * NLAYERS + t0]);

  if (MODE == 0) {
    const float inv = 0.001953125f;  // 1/sqrt(2^18) = 1/512 exactly
#pragma unroll
    for (int r4 = 0; r4 < 16; ++r4) {
      const int off = tbase + r4 * 128 + lane * 2;
      const unsigned d0 = (unsigned)off, d1 = (unsigned)off + 1u;
      int hp0 = 0, hp1 = 0;
#pragma unroll
      for (int u = 0; u < NQ; ++u) {
        const unsigned mu = smask[u];
        const unsigned f0 = (d0 >> (NQ - 1 - u)) & 1u;
        const unsigned f1 = (d1 >> (NQ - 1 - u)) & 1u;
        hp0 += __popc(mu & (d0 ^ (0u - f0)));
        hp1 += __popc(mu & (d1 ^ (0u - f1)));
      }
      *(unsigned short*)(hp8 + bbase + off) = (unsigned short)(hp0 | (hp1 << 8));
      const float2 p0 = ptab[hp0], p1 = ptab[hp1];
      v[2 * r4].x = p0.x * inv;     v[2 * r4].y = p0.y * inv;
      v[2 * r4 + 1].x = p1.x * inv; v[2 * r4 + 1].y = p1.y * inv;
    }
  } else {
#pragma unroll
    for (int r4 = 0; r4 < 16; ++r4) {
      const float4 t = *(const float4*)&state[bbase + tbase + r4 * 128 + lane * 2];
      v[2 * r4].x = t.x; v[2 * r4].y = t.y;
      v[2 * r4 + 1].x = t.z; v[2 * r4 + 1].y = t.w;
    }
  }

  mixLow(v, cs0, sn0);

  if (MODE == 1) {
    const float cs1 = cosf(betas[b * NLAYERS + t0 + 1]);
    const float sn1 = sinf(betas[b * NLAYERS + t0 + 1]);
#pragma unroll
    for (int r4 = 0; r4 < 16; ++r4) {
      const unsigned short h2 =
          *(const unsigned short*)(hp8 + bbase + tbase + r4 * 128 + lane * 2);
      pmul(v[2 * r4], ptab[h2 & 255]);
      pmul(v[2 * r4 + 1], ptab[h2 >> 8]);
    }
    mixLow(v, cs1, sn1);
  }

  if (MODE == 2) {
    float acc = 0.f;
#pragma unroll
    for (int r4 = 0; r4 < 16; ++r4) {
      const unsigned short h2 =
          *(const unsigned short*)(hp8 + bbase + tbase + r4 * 128 + lane * 2);
      const float2 a = v[2 * r4], bb = v[2 * r4 + 1];
      acc += (a.x * a.x + a.y * a.y) * (float)(h2 & 255);
      acc += (bb.x * bb.x + bb.y * bb.y) * (float)(h2 >> 8);
    }
#pragma unroll
    for (int m = 1; m <= 32; m <<= 1) acc += __shfl_xor(acc, m, 64);
    if (lane == 0) atomicAdd(out + b, acc);
  } else {
#pragma unroll
    for (int r4 = 0; r4 < 16; ++r4) {
      float4 t;
      t.x = v[2 * r4].x; t.y = v[2 * r4].y;
      t.z = v[2 * r4 + 1].x; t.w = v[2 * r4 + 1].y;
      *(float4*)&state[bbase + tbase + r4 * 128 + lane * 2] = t;
    }
  }
}

// B pass: load comb tile, mixHigh(beta[t0]), phase, mixHigh(beta[t0+1]), store
__global__ __launch_bounds__(256)
void k_passB(const float* __restrict__ betas, const unsigned char* __restrict__ hp8,
             float2* __restrict__ state, int t0) {
  __shared__ float2 ptab[160];
  const int tid = threadIdx.x;
  if (tid < 160) {
    float s, c; sincosf((float)tid, &s, &c);
    ptab[tid] = make_float2(c, -s);
  }
  __syncthreads();
  const int T = blockIdx.x * 4 + (tid >> 6);
  const int b = T >> 7;
  const int g = T & 127;
  const int lane = tid & 63;
  const size_t bbase = (size_t)b * QDIM;
  const int hlo = lane >> 3;
  const int low3 = lane & 7;

  float2 v[32];
  const float cs0 = cosf(betas[b * NLAYERS + t0]);
  const float sn0 = sinf(betas[b * NLAYERS + t0]);
  const float cs1 = cosf(betas[b * NLAYERS + t0 + 1]);
  const float sn1 = sinf(betas[b * NLAYERS + t0 + 1]);

#pragma unroll
  for (int r4 = 0; r4 < 16; ++r4) {
    const int h = (r4 << 3) | hlo;
    const int off = (h << 11) | (g << 4) | (low3 << 1);
    const float4 t = *(const float4*)&state[bbase + off];
    v[2 * r4].x = t.x; v[2 * r4].y = t.y;
    v[2 * r4 + 1].x = t.z; v[2 * r4 + 1].y = t.w;
  }

  mixHigh(v, cs0, sn0);

#pragma unroll
  for (int r4 = 0; r4 < 16; ++r4) {
    const int h = (r4 << 3) | hlo;
    const int off = (h << 11) | (g << 4) | (low3 << 1);
    const unsigned short h2 = *(const unsigned short*)(hp8 + bbase + off);
    pmul(v[2 * r4], ptab[h2 & 255]);
    pmul(v[2 * r4 + 1], ptab[h2 >> 8]);
  }

  mixHigh(v, cs1, sn1);

#pragma unroll
  for (int r4 = 0; r4 < 16; ++r4) {
    const int h = (r4 << 3) | hlo;
    const int off = (h << 11) | (g << 4) | (low3 << 1);
    float4 t;
    t.x = v[2 * r4].x; t.y = v[2 * r4].y;
    t.z = v[2 * r4 + 1].x; t.w = v[2 * r4 + 1].y;
    *(float4*)&state[bbase + off] = t;
  }
}

extern "C" void kernel_launch(void* const* d_in, const int* in_sizes, int n_in,
                              void* d_out, int out_size, void* d_ws, size_t ws_size,
                              hipStream_t stream) {
  const float* betas = (const float*)d_in[0];  // [8][4]
  const float* adj   = (const float*)d_in[1];  // [8][18][18]
  float* out = (float*)d_out;                  // [8] float32
  char* ws = (char*)d_ws;
  float2* state = (float2*)ws;                                         // 16 MB
  unsigned char* hp8 = (unsigned char*)(ws + (size_t)NBATCH * QDIM * sizeof(float2));  // 2 MB
  unsigned* masks = (unsigned*)(ws + (size_t)NBATCH * QDIM * (sizeof(float2) + 1));

  hipMemsetAsync(d_out, 0, out_size * sizeof(float), stream);
  k_masks<<<NBATCH, 32, 0, stream>>>(adj, masks);

  dim3 grid(256), blk(256);
  // P1: D1 + M1.low          P2: M1.high, D2, M2.high
  // P3: M2.low, D3, M3.low   P4: M3.high, D4, M4.high
  // P5: M4.low + energy
  k_passA<0><<<grid, blk, 0, stream>>>(betas, masks, hp8, state, out, 0);
  k_passB<<<grid, blk, 0, stream>>>(betas, hp8, state, 0);
  k_passA<1><<<grid, blk, 0, stream>>>(betas, masks, hp8, state, out, 1);
  k_passB<<<grid, blk, 0, stream>>>(betas, hp8, state, 2);
  k_passA<2><<<grid, blk, 0, stream>>>(betas, masks, hp8, state, out, 3);
}